// Round 9
// baseline (782.536 us; speedup 1.0000x reference)
//
#include <hip/hip_runtime.h>

// C51 distributional Q target, R9: BARRIER-FREE restructure.
// One wave = one independent 16-row network evaluation. GEMM B-operand is the
// wave's single 16-row tile; A-operand = weight rows streamed from L2 via a
// depth-8 register ring. LN/softmax close in-wave (shfl_xor 16/32). Wave-
// private 16KB LDS region (X->H1->H2->H3->proj), no __syncthreads anywhere;
// within-wave DS ordering + lgkmcnt(0) fences at tenant transitions.
// Block = 2 waves (128 thr) -> 32KB LDS -> 5 blocks/CU = 10 waves/CU.

#define THREADS 128
#define PREP_THREADS 256

typedef __attribute__((ext_vector_type(8))) short short8v;
typedef __attribute__((ext_vector_type(4))) float f32x4;

__device__ __forceinline__ unsigned short f2bf(float f) {
  union { float f; unsigned u; } v; v.f = f;
  unsigned u = v.u;
  u += 0x7fffu + ((u >> 16) & 1u);   // RNE
  return (unsigned short)(u >> 16);
}
// HW packed fp32->bf16 (RNE), 1 VALU inst for 2 values
__device__ __forceinline__ unsigned pack2bf(float a, float b) {
  unsigned r;
  asm("v_cvt_pk_bf16_f32 %0, %1, %2" : "=v"(r) : "v"(a), "v"(b));
  return r;
}

// wave-local fence: all outstanding DS ops complete before anything below
__device__ __forceinline__ void lds_fence() {
  asm volatile("s_waitcnt lgkmcnt(0)" ::: "memory");
  __builtin_amdgcn_sched_barrier(0);
}

// ---------------- prep: weights fp32 [K][N] -> bf16 [N][K] in ws -------------
// W1T @0 (512x160), W2T @81920 (256x512), W3T @212992 (128x256),
// W4T @245760 (256x128, rows n>=251 zero-padded)
__global__ void prep_kernel(const float* __restrict__ W1, const float* __restrict__ W2,
                            const float* __restrict__ W3, const float* __restrict__ W4,
                            unsigned short* __restrict__ ws) {
  int i = blockIdx.x * PREP_THREADS + threadIdx.x;
  if (i < 81920) {
    int n = i / 160, k = i - n * 160;
    ws[i] = f2bf(W1[k * 512 + n]);
  } else if (i < 212992) {
    int j = i - 81920; int n = j >> 9, k = j & 511;
    ws[i] = f2bf(W2[k * 256 + n]);
  } else if (i < 245760) {
    int j = i - 212992; int n = j >> 8, k = j & 255;
    ws[i] = f2bf(W3[k * 128 + n]);
  } else if (i < 278528) {
    int j = i - 245760; int n = j >> 7, k = j & 127;
    ws[i] = (n < 251) ? f2bf(W4[k * 251 + n]) : (unsigned short)0;
  }
}

// Per-wave GEMM: acc[ft] += WT[ft*16+..][k] * H[lm][k] over ALL NT ft-tiles.
// MFMA 16x16x32 bf16: A = weight rows (m=feature), B = 16 act rows.
// D: lane&15 = batch row, (lane>>4)*4+reg = feature-in-tile.
// a-frags: depth-8 register ring (slot = ft&7, NT%8==0), prefetch 8 items
// ahead. b-frags: double-buffered, prefetched one full ks-body ahead.
// Fully unrolled; all ring indices compile-time.
template<int KD, int NT>
__device__ __forceinline__ void gemm_wave(const unsigned short* __restrict__ WT,
                                          const unsigned char* __restrict__ Hb,
                                          f32x4 (&acc)[NT]) {
  constexpr int KS = KD / 32, NIT = KS * NT;
  const int lane = threadIdx.x & 63;
  const int lm = lane & 15, kg = lane >> 4;
  const int swz = (lm & 7) << 4;
  const int bbase = lm * (KD * 2) + kg * 16;
  const int boffE = bbase ^ swz;          // even-ks base (+pair*128)
  const int boffO = (bbase + 64) ^ swz;   // odd-ks base
  const int woff = lm * KD + kg * 8;

  short8v abuf[8];
  short8v bcur, bnxt;

  bcur = *(const short8v*)(Hb + boffE);
  if constexpr (KS > 1) bnxt = *(const short8v*)(Hb + boffO);
#pragma unroll
  for (int f = 0; f < 8; ++f)           // NT >= 8 always
    abuf[f] = *(const short8v*)(WT + woff + f * (16 * KD));

#pragma unroll
  for (int ks = 0; ks < KS; ++ks) {
#pragma unroll
    for (int ft = 0; ft < NT; ++ft) {
      acc[ft] = __builtin_amdgcn_mfma_f32_16x16x32_bf16(abuf[ft & 7], bcur,
                                                        acc[ft], 0, 0, 0);
      const int nit = ks * NT + ft + 8;   // prefetch 8 items ahead
      if (nit < NIT) {
        const int nks = nit / NT, nf = nit % NT;
        abuf[ft & 7] =
            *(const short8v*)(WT + woff + nf * (16 * KD) + nks * 32);
      }
    }
    if (ks + 1 < KS) {
      bcur = bnxt;
      if (ks + 2 < KS) {
        const int a = ((ks + 2) & 1) ? boffO : boffE;
        bnxt = *(const short8v*)(Hb + a + ((ks + 2) >> 1) * 128);
      }
    }
  }
}

// bias + LayerNorm + SiLU fully in-wave (shfl reduction, no LDS), then one
// packed b64 store per ft into swizzled wave-private [16][ND] bf16.
template<int ND, int NT>
__device__ __forceinline__ void ln_silu_store(
    f32x4 (&acc)[NT],
    const float* __restrict__ bias, const float* __restrict__ g,
    const float* __restrict__ be, unsigned char* __restrict__ Hb)
{
  const int lane = threadIdx.x & 63;
  const int lm = lane & 15, kg = lane >> 4;
  float s = 0.f, q = 0.f;
#pragma unroll
  for (int ft = 0; ft < NT; ++ft) {
    const int f0 = ft * 16 + kg * 4;
    const f32x4 bb = *(const f32x4*)(bias + f0);
#pragma unroll
    for (int rg = 0; rg < 4; ++rg) {
      float x = acc[ft][rg] + bb[rg];
      acc[ft][rg] = x;
      s += x; q += x * x;
    }
  }
  s += __shfl_xor(s, 16); s += __shfl_xor(s, 32);
  q += __shfl_xor(q, 16); q += __shfl_xor(q, 32);
  const float mean = s * (1.0f / ND);
  const float var  = q * (1.0f / ND) - mean * mean;
  const float rstd = rsqrtf(var + 1e-5f);
#pragma unroll
  for (int ft = 0; ft < NT; ++ft) {
    const int f0 = ft * 16 + kg * 4;
    const f32x4 g4 = *(const f32x4*)(g + f0);
    const f32x4 e4 = *(const f32x4*)(be + f0);
    float h[4];
#pragma unroll
    for (int rg = 0; rg < 4; ++rg) {
      float y = (acc[ft][rg] - mean) * rstd * g4[rg] + e4[rg];
      h[rg] = y * (1.0f / (1.0f + __expf(-y)));
    }
    uint2 w; w.x = pack2bf(h[0], h[1]); w.y = pack2bf(h[2], h[3]);
    const int byte = (lm * (ND * 2) + f0 * 2) ^ ((lm & 7) << 4);
    *(uint2*)(Hb + byte) = w;
  }
}

__global__ __launch_bounds__(THREADS, 2) void fused_kernel(
    const float* __restrict__ obs, const float* __restrict__ actions,
    const float* __restrict__ rewards, const float* __restrict__ bootstrap,
    const float* __restrict__ discount, const float* __restrict__ q_support,
    const float* __restrict__ b1, const float* __restrict__ g1, const float* __restrict__ be1,
    const float* __restrict__ b2, const float* __restrict__ g2, const float* __restrict__ be2,
    const float* __restrict__ b3, const float* __restrict__ g3, const float* __restrict__ be3,
    const float* __restrict__ b4,
    const unsigned short* __restrict__ ws,
    float* __restrict__ out)
{
  __shared__ __align__(16) unsigned char smem[32768];  // 2 waves x 16KB
  const int tid  = threadIdx.x;
  const int wid  = tid >> 6;
  const int lane = tid & 63;
  const int lm   = lane & 15;
  const int kg   = lane >> 4;
  const int row0 = (blockIdx.x * 2 + wid) * 16;
  unsigned char* R = smem + wid * 16384;   // wave-private region

  const unsigned short* W1T = ws;
  const unsigned short* W2T = ws + 81920;
  const unsigned short* W3T = ws + 212992;
  const unsigned short* W4T = ws + 245760;

  // ---- stage X = concat(obs, actions) bf16 [16][160] swz (640 float4) ----
#pragma unroll
  for (int i = 0; i < 10; ++i) {
    const int qq = i * 64 + lane;          // 40 float4 per row
    const int r  = qq / 40;
    const int c4 = (qq - r * 40) * 4;
    float4 v;
    if (c4 < 128) v = *(const float4*)(obs + (size_t)(row0 + r) * 128 + c4);
    else          v = *(const float4*)(actions + (size_t)(row0 + r) * 32 + (c4 - 128));
    uint2 w; w.x = pack2bf(v.x, v.y); w.y = pack2bf(v.z, v.w);
    const int byte = (r * 320 + c4 * 2) ^ ((r & 7) << 4);
    *(uint2*)(R + byte) = w;
  }
  lds_fence();

  // ---- layer 1: 512 feats, K=160 ----
  f32x4 acc1[32];
#pragma unroll
  for (int i = 0; i < 32; ++i) acc1[i] = f32x4{0.f, 0.f, 0.f, 0.f};
  gemm_wave<160, 32>(W1T, R, acc1);
  lds_fence();                       // X reads drained before H1 writes
  ln_silu_store<512, 32>(acc1, b1, g1, be1, R);
  lds_fence();

  // ---- layer 2: 256 feats, K=512 ----
  f32x4 acc2[16];
#pragma unroll
  for (int i = 0; i < 16; ++i) acc2[i] = f32x4{0.f, 0.f, 0.f, 0.f};
  gemm_wave<512, 16>(W2T, R, acc2);
  lds_fence();
  ln_silu_store<256, 16>(acc2, b2, g2, be2, R);
  lds_fence();

  // ---- layer 3: 128 feats, K=256 ----
  f32x4 acc3[8];
#pragma unroll
  for (int i = 0; i < 8; ++i) acc3[i] = f32x4{0.f, 0.f, 0.f, 0.f};
  gemm_wave<256, 8>(W3T, R, acc3);
  lds_fence();
  ln_silu_store<128, 8>(acc3, b3, g3, be3, R);
  lds_fence();

  // ---- layer 4: logits, 256pad feats, K=128 ----
  f32x4 acc4[16];
#pragma unroll
  for (int i = 0; i < 16; ++i) acc4[i] = f32x4{0.f, 0.f, 0.f, 0.f};
  gemm_wave<128, 16>(W4T, R, acc4);

  // bias + mask (tile 15 straddles 251: guarded scalar loads)
#pragma unroll
  for (int ft = 0; ft < 16; ++ft) {
    const int f0 = ft * 16 + kg * 4;
    if (ft < 15) {
      const f32x4 bv = *(const f32x4*)(b4 + f0);
#pragma unroll
      for (int rg = 0; rg < 4; ++rg) acc4[ft][rg] += bv[rg];
    } else {
#pragma unroll
      for (int rg = 0; rg < 4; ++rg) {
        const int f = f0 + rg;
        acc4[ft][rg] = (f < 251) ? (acc4[ft][rg] + b4[f]) : -1e30f;
      }
    }
  }

  // ---- softmax over 251 feats per row, fully in-wave ----
  float m = -1e30f;
#pragma unroll
  for (int ft = 0; ft < 16; ++ft)
#pragma unroll
    for (int rg = 0; rg < 4; ++rg) m = fmaxf(m, acc4[ft][rg]);
  m = fmaxf(m, __shfl_xor(m, 16));
  m = fmaxf(m, __shfl_xor(m, 32));
  float E = 0.f;
#pragma unroll
  for (int ft = 0; ft < 16; ++ft)
#pragma unroll
    for (int rg = 0; rg < 4; ++rg) {
      const float e = __expf(acc4[ft][rg] - m);
      acc4[ft][rg] = e;
      E += e;
    }
  E += __shfl_xor(E, 16); E += __shfl_xor(E, 32);
  const float inv = 1.0f / E;

  // ---- zero proj buffer (region R; H3 reads already drained) ----
  lds_fence();
  float4* Rz = (float4*)R;
  for (int i = lane; i < 1004; i += 64) Rz[i] = float4{0.f, 0.f, 0.f, 0.f};
  lds_fence();

  // per-row scalars (each lane owns row lm)
  const float rw = rewards[row0 + lm];
  const float bt = bootstrap[row0 + lm];
  const float dc = discount[row0 + lm];
  const float bd = __fmul_rn(bt, dc);

  // ---- C51 projection scatter (bit-exact add/mul sequence; *INVDZ ok:
  // two-point interpolation is continuous in b, error O(1e-7)) ----
  constexpr float DZF = 20.0f / 250.0f;
  constexpr float INVDZ = 1.0f / DZF;
  float* projL = (float*)R;
  const int base = lm * 251;
#pragma unroll
  for (int ft = 0; ft < 16; ++ft) {
    const int f0 = ft * 16 + kg * 4;
    f32x4 z4 = f32x4{0.f, 0.f, 0.f, 0.f};
    if (ft < 15) z4 = *(const f32x4*)(q_support + f0);
#pragma unroll
    for (int rg = 0; rg < 4; ++rg) {
      const int f = f0 + rg;
      if (f < 251) {
        const float z = (ft < 15) ? z4[rg] : q_support[f];
        const float p = acc4[ft][rg] * inv;
        float t = __fadd_rn(rw, __fmul_rn(bd, z));
        t = fminf(fmaxf(t, -10.0f), 10.0f);
        const float bfr = __fmul_rn(__fsub_rn(t, -10.0f), INVDZ);
        const float fl = floorf(bfr), fu = ceilf(bfr);
        int l = (int)fl, u = (int)fu;
        if (fl == fu) { if (l > 0) --l; else ++u; }
        atomicAdd(projL + base + l, p * ((float)u - bfr));
        atomicAdd(projL + base + u, p * (bfr - (float)l));
      }
    }
  }
  lds_fence();

  // ---- write out: wave slice contiguous (16*251 floats = 1004 float4) ----
  const float4* ps = (const float4*)R;
  float4* po = (float4*)(out + (size_t)row0 * 251);
  for (int i = lane; i < 1004; i += 64) po[i] = ps[i];
}

extern "C" void kernel_launch(void* const* d_in, const int* in_sizes, int n_in,
                              void* d_out, int out_size, void* d_ws, size_t ws_size,
                              hipStream_t stream) {
  const float* obs  = (const float*)d_in[0];
  const float* act  = (const float*)d_in[1];
  const float* rew  = (const float*)d_in[2];
  const float* boot = (const float*)d_in[3];
  const float* disc = (const float*)d_in[4];
  const float* zs   = (const float*)d_in[5];
  const float* W1   = (const float*)d_in[6];
  const float* b1   = (const float*)d_in[7];
  const float* g1   = (const float*)d_in[8];
  const float* be1  = (const float*)d_in[9];
  const float* W2   = (const float*)d_in[10];
  const float* b2   = (const float*)d_in[11];
  const float* g2   = (const float*)d_in[12];
  const float* be2  = (const float*)d_in[13];
  const float* W3   = (const float*)d_in[14];
  const float* b3   = (const float*)d_in[15];
  const float* g3   = (const float*)d_in[16];
  const float* be3  = (const float*)d_in[17];
  const float* W4   = (const float*)d_in[18];
  const float* b4   = (const float*)d_in[19];
  unsigned short* wsp = (unsigned short*)d_ws;

  const int Bn = in_sizes[2];          // batch = 131072
  prep_kernel<<<(278528 + PREP_THREADS - 1) / PREP_THREADS, PREP_THREADS, 0, stream>>>(
      W1, W2, W3, W4, wsp);
  fused_kernel<<<Bn / 32, THREADS, 0, stream>>>(obs, act, rew, boot, disc, zs,
      b1, g1, be1, b2, g2, be2, b3, g3, be3, b4, wsp, (float*)d_out);
}

// Round 10
// 524.197 us; speedup vs baseline: 1.4928x; 1.4928x over previous
//
#include <hip/hip_runtime.h>

// C51 distributional Q target, R10: R5 shell (32 rows/block, 4 waves,
// operand-swapped MFMA, in-register LN/SiLU/softmax, time-muxed act LDS)
// + ASYNC WEIGHT STAGING for layers 2-4: weights pre-packed in MFMA-fragment
// order; each wave double-buffers its 4KB/chunk feature-slice in LDS via
// global_load_lds (width 16), counted vmcnt waits, no extra barriers.
// Layer 1 keeps the direct-register path (K=160). 67.2KB LDS -> 2 blocks/CU.

#define THREADS 256
#define PREP_THREADS 256

typedef __attribute__((ext_vector_type(8))) short short8v;
typedef __attribute__((ext_vector_type(4))) float f32x4;

__device__ __forceinline__ unsigned short f2bf(float f) {
  union { float f; unsigned u; } v; v.f = f;
  unsigned u = v.u;
  u += 0x7fffu + ((u >> 16) & 1u);   // RNE
  return (unsigned short)(u >> 16);
}
__device__ __forceinline__ unsigned pack2bf(float a, float b) {
  unsigned r;
  asm("v_cvt_pk_bf16_f32 %0, %1, %2" : "=v"(r) : "v"(a), "v"(b));
  return r;
}

// async global->LDS, 16B per lane; lds dest wave-uniform base + lane*16
__device__ __forceinline__ void gload16(const void* g, void* l) {
  __builtin_amdgcn_global_load_lds(
      (const __attribute__((address_space(1))) unsigned int*)g,
      (__attribute__((address_space(3))) unsigned int*)l, 16, 0, 0);
}
template<int N>
__device__ __forceinline__ void wait_vmcnt() {
  if constexpr (N == 0)      asm volatile("s_waitcnt vmcnt(0)" ::: "memory");
  else if constexpr (N == 2) asm volatile("s_waitcnt vmcnt(2)" ::: "memory");
  else if constexpr (N == 4) asm volatile("s_waitcnt vmcnt(4)" ::: "memory");
}

// ---------------- prep: weights -> ws ----------------------------------------
// W1T @0: [n][k] 512x160 (direct path).
// W2S @81920: staged-frag order, 16 ks-chunks x 16 ftg x 64 lane x 8:
//   elem(ks,ftg,lane,e) = W2[ks*32+(lane>>4)*8+e][ftg*16+(lane&15)]
// W3S @212992: 8 chunks x 8 ftg x 64 x 8 (same rule, W3, 128 feats)
// W4S @245760: 4 chunks x 16 ftg x 64 x 8 (W4, n>=251 -> 0)
__global__ void prep_kernel(const float* __restrict__ W1, const float* __restrict__ W2,
                            const float* __restrict__ W3, const float* __restrict__ W4,
                            unsigned short* __restrict__ ws) {
  int i = blockIdx.x * PREP_THREADS + threadIdx.x;
  if (i < 81920) {
    int n = i / 160, k = i - n * 160;
    ws[i] = f2bf(W1[k * 512 + n]);
  } else if (i < 212992) {
    int j = i - 81920;
    int e = j & 7, lane = (j >> 3) & 63, ftg = (j >> 9) & 15, ks = j >> 13;
    int n = ftg * 16 + (lane & 15);
    int k = ks * 32 + ((lane >> 4) << 3) + e;
    ws[i] = f2bf(W2[k * 256 + n]);
  } else if (i < 245760) {
    int j = i - 212992;
    int e = j & 7, lane = (j >> 3) & 63, ftg = (j >> 9) & 7, ks = j >> 12;
    int n = ftg * 16 + (lane & 15);
    int k = ks * 32 + ((lane >> 4) << 3) + e;
    ws[i] = f2bf(W3[k * 128 + n]);
  } else if (i < 278528) {
    int j = i - 245760;
    int e = j & 7, lane = (j >> 3) & 63, ftg = (j >> 9) & 15, ks = j >> 13;
    int n = ftg * 16 + (lane & 15);
    int k = ks * 32 + ((lane >> 4) << 3) + e;
    ws[i] = (n < 251) ? f2bf(W4[k * 251 + n]) : (unsigned short)0;
  }
}

// LDS (bytes): act region R @0 (32KB, time-muxed X->H1->H2->H3->proj);
// weight staging W @32768 (4 waves x 2 x 4KB); zs/b4/red after.
#define OFF_R   0
#define OFF_W   32768
#define OFF_ZS  65536
#define OFF_B4  66560
#define OFF_RED 67584
#define LDS_TOTAL 68736

// ---- direct-register GEMM for layer 1 (K=160), R7-proven -------------------
template<int KD, int NFT, int FPG, int DEPTH>
__device__ __forceinline__ void gemm_w(const unsigned short* __restrict__ WT,
                                       const unsigned char* __restrict__ Hb,
                                       int fbase, f32x4 (&acc)[NFT][2]) {
  const int lane = threadIdx.x & 63;
  const int lm = lane & 15, kg = lane >> 4;
  constexpr int KS  = KD / 32;
  constexpr int G   = NFT / FPG;
  constexpr int NIT = KS * G;
  constexpr int PF  = DEPTH - 1;

  const int woff0 = (fbase + lm) * KD + kg * 8;
  int boff[2][2];
#pragma unroll
  for (int rt = 0; rt < 2; ++rt) {
    const int r = rt * 16 + lm;
    const int swz = (r & 7) << 4;
    const int base = r * (KD * 2) + kg * 16;
    boff[rt][0] = base ^ swz;
    boff[rt][1] = (base + 64) ^ swz;
  }
  short8v abuf[DEPTH][FPG];
  short8v bbuf[DEPTH][2];
#pragma unroll
  for (int ks = 0; ks < PF && ks < KS; ++ks) {
    const int koff = (ks >> 1) * 128;
#pragma unroll
    for (int rt = 0; rt < 2; ++rt)
      bbuf[ks % DEPTH][rt] = *(const short8v*)(Hb + boff[rt][ks & 1] + koff);
  }
#pragma unroll
  for (int p = 0; p < PF && p < NIT; ++p) {
    const int g = p % G, ks = p / G;
#pragma unroll
    for (int f = 0; f < FPG; ++f)
      abuf[p % DEPTH][f] =
          *(const short8v*)(WT + woff0 + (g * FPG + f) * (16 * KD) + ks * 32);
  }
#pragma unroll
  for (int it = 0; it < NIT; ++it) {
    const int ks = it / G, g = it % G;
    if (g == 0 && ks + PF < KS) {
      const int nks = ks + PF;
      const int koff = (nks >> 1) * 128;
#pragma unroll
      for (int rt = 0; rt < 2; ++rt)
        bbuf[nks % DEPTH][rt] = *(const short8v*)(Hb + boff[rt][nks & 1] + koff);
    }
    if (it + PF < NIT) {
      const int nit = it + PF;
      const int ng = nit % G, nks = nit / G;
#pragma unroll
      for (int f = 0; f < FPG; ++f)
        abuf[nit % DEPTH][f] =
            *(const short8v*)(WT + woff0 + (ng * FPG + f) * (16 * KD) + nks * 32);
    }
#pragma unroll
    for (int f = 0; f < FPG; ++f) {
      const int ft = g * FPG + f;
      acc[ft][0] = __builtin_amdgcn_mfma_f32_16x16x32_bf16(
          abuf[it % DEPTH][f], bbuf[ks % DEPTH][0], acc[ft][0], 0, 0, 0);
      acc[ft][1] = __builtin_amdgcn_mfma_f32_16x16x32_bf16(
          abuf[it % DEPTH][f], bbuf[ks % DEPTH][1], acc[ft][1], 0, 0, 0);
    }
  }
}

// ---- async-staged GEMM for layers 2-4 --------------------------------------
// WS = staged layer base (frag order). Wave fq stages its NFT-KB slice per
// 32-k chunk into wbuf (2 buffers), double-buffered, counted vmcnt waits.
// a-frag ds_read = wbuf + buf*NFT*1024 + ft*1024 + lane*16 (conflict-free).
template<int KD, int NFT>
__device__ __forceinline__ void gemm_staged(const unsigned short* __restrict__ WS,
                                            const unsigned char* __restrict__ Hact,
                                            unsigned char* __restrict__ wbuf,
                                            int fq, f32x4 (&acc)[NFT][2]) {
  constexpr int KS = KD / 32;
  constexpr int CSTRIDE = 4 * NFT * 512;   // elems per global chunk (4 waves)
  const int lane = threadIdx.x & 63;
  const int lm = lane & 15, kg = lane >> 4;
  int boff[2][2];
#pragma unroll
  for (int rt = 0; rt < 2; ++rt) {
    const int r = rt * 16 + lm;
    const int swz = (r & 7) << 4;
    const int base = r * (KD * 2) + kg * 16;
    boff[rt][0] = base ^ swz;
    boff[rt][1] = (base + 64) ^ swz;
  }
  const unsigned short* gbase = WS + (size_t)fq * (NFT * 512) + (size_t)lane * 8;

  // prologue: stage chunks 0 and 1
#pragma unroll
  for (int c = 0; c < 2 && c < KS; ++c)
#pragma unroll
    for (int j = 0; j < NFT; ++j)
      gload16(gbase + (size_t)c * CSTRIDE + j * 512,
              wbuf + (c & 1) * (NFT * 1024) + j * 1024);

#pragma unroll
  for (int c = 0; c < KS; ++c) {
    if (c + 1 < KS) wait_vmcnt<NFT>(); else wait_vmcnt<0>();
    short8v a[NFT], b[2];
#pragma unroll
    for (int ft = 0; ft < NFT; ++ft)
      a[ft] = *(const short8v*)(wbuf + (c & 1) * (NFT * 1024) + ft * 1024 + lane * 16);
    const int koff = (c >> 1) * 128;
#pragma unroll
    for (int rt = 0; rt < 2; ++rt)
      b[rt] = *(const short8v*)(Hact + boff[rt][c & 1] + koff);
#pragma unroll
    for (int ft = 0; ft < NFT; ++ft) {
      acc[ft][0] = __builtin_amdgcn_mfma_f32_16x16x32_bf16(a[ft], b[0], acc[ft][0], 0, 0, 0);
      acc[ft][1] = __builtin_amdgcn_mfma_f32_16x16x32_bf16(a[ft], b[1], acc[ft][1], 0, 0, 0);
    }
    __builtin_amdgcn_sched_barrier(0);   // WAR: reads above, re-stage below
    if (c + 2 < KS) {
#pragma unroll
      for (int j = 0; j < NFT; ++j)
        gload16(gbase + (size_t)(c + 2) * CSTRIDE + j * 512,
                wbuf + (c & 1) * (NFT * 1024) + j * 1024);
    }
  }
}

// bias + LayerNorm + SiLU in registers, packed b64 store to swizzled act LDS.
template<int ND, int NFT>
__device__ __forceinline__ void ln_silu_store(
    f32x4 (&acc)[NFT][2],
    const float* __restrict__ bias, const float* __restrict__ g,
    const float* __restrict__ be, unsigned char* __restrict__ Hb,
    float* __restrict__ redL, int fbase, int fq)
{
  const int lane = threadIdx.x & 63;
  const int lm = lane & 15, kg = lane >> 4;
  float s[2] = {0.f, 0.f}, q[2] = {0.f, 0.f};
#pragma unroll
  for (int ft = 0; ft < NFT; ++ft) {
    const int f0 = fbase + ft * 16 + kg * 4;
    const f32x4 bb = *(const f32x4*)(bias + f0);
#pragma unroll
    for (int rt = 0; rt < 2; ++rt)
#pragma unroll
      for (int rg = 0; rg < 4; ++rg) {
        float x = acc[ft][rt][rg] + bb[rg];
        acc[ft][rt][rg] = x;
        s[rt] += x; q[rt] += x * x;
      }
  }
#pragma unroll
  for (int rt = 0; rt < 2; ++rt) {
    s[rt] += __shfl_xor(s[rt], 16); s[rt] += __shfl_xor(s[rt], 32);
    q[rt] += __shfl_xor(q[rt], 16); q[rt] += __shfl_xor(q[rt], 32);
  }
  if (lane < 16) {
#pragma unroll
    for (int rt = 0; rt < 2; ++rt) {
      redL[(rt * 16 + lm) * 9 + fq * 2    ] = s[rt];
      redL[(rt * 16 + lm) * 9 + fq * 2 + 1] = q[rt];
    }
  }
  __syncthreads();
  float mean[2], rstd[2];
#pragma unroll
  for (int rt = 0; rt < 2; ++rt) {
    const int row = rt * 16 + lm;
    float S = 0.f, Q = 0.f;
#pragma unroll
    for (int w = 0; w < 4; ++w) {
      S += redL[row * 9 + w * 2];
      Q += redL[row * 9 + w * 2 + 1];
    }
    float m = S * (1.0f / ND);
    float v = Q * (1.0f / ND) - m * m;
    mean[rt] = m; rstd[rt] = rsqrtf(v + 1e-5f);
  }
#pragma unroll
  for (int ft = 0; ft < NFT; ++ft) {
    const int f0 = fbase + ft * 16 + kg * 4;
    const f32x4 g4 = *(const f32x4*)(g + f0);
    const f32x4 e4 = *(const f32x4*)(be + f0);
#pragma unroll
    for (int rt = 0; rt < 2; ++rt) {
      const int row = rt * 16 + lm;
      float h[4];
#pragma unroll
      for (int rg = 0; rg < 4; ++rg) {
        float y = (acc[ft][rt][rg] - mean[rt]) * rstd[rt] * g4[rg] + e4[rg];
        h[rg] = y * (1.0f / (1.0f + __expf(-y)));
      }
      uint2 w; w.x = pack2bf(h[0], h[1]); w.y = pack2bf(h[2], h[3]);
      int byte = row * (ND * 2) + f0 * 2;
      byte ^= ((row & 7) << 4);
      *(uint2*)(Hb + byte) = w;
    }
  }
}

__global__ __launch_bounds__(THREADS, 2) void fused_kernel(
    const float* __restrict__ obs, const float* __restrict__ actions,
    const float* __restrict__ rewards, const float* __restrict__ bootstrap,
    const float* __restrict__ discount, const float* __restrict__ q_support,
    const float* __restrict__ b1, const float* __restrict__ g1, const float* __restrict__ be1,
    const float* __restrict__ b2, const float* __restrict__ g2, const float* __restrict__ be2,
    const float* __restrict__ b3, const float* __restrict__ g3, const float* __restrict__ be3,
    const float* __restrict__ b4,
    const unsigned short* __restrict__ ws,
    float* __restrict__ out)
{
  __shared__ __align__(16) unsigned char smem[LDS_TOTAL];
  const int tid  = threadIdx.x;
  const int fq   = tid >> 6;          // wave = feature-quarter, 0..3
  const int lane = tid & 63;
  const int lm   = lane & 15;
  const int kg   = lane >> 4;
  const int row0 = blockIdx.x * 32;

  const unsigned short* W1T = ws;
  const unsigned short* W2S = ws + 81920;
  const unsigned short* W3S = ws + 212992;
  const unsigned short* W4S = ws + 245760;

  float* zsL  = (float*)(smem + OFF_ZS);
  float* b4L  = (float*)(smem + OFF_B4);
  float* redL = (float*)(smem + OFF_RED);
  unsigned char* wbuf = smem + OFF_W + fq * 8192;   // wave-private 2x4KB

  float rw[2], bt[2], dc[2];
#pragma unroll
  for (int rt = 0; rt < 2; ++rt) {
    const int r = row0 + rt * 16 + lm;
    rw[rt] = rewards[r]; bt[rt] = bootstrap[r]; dc[rt] = discount[r];
  }
  zsL[tid] = (tid < 251) ? q_support[tid] : 0.f;
  b4L[tid] = (tid < 251) ? b4[tid] : 0.f;

  // stage X = concat(obs, actions) bf16 [32][160], swizzled (1280 uint2)
  {
    unsigned char* Xb = smem + OFF_R;
#pragma unroll
    for (int it = 0; it < 5; ++it) {
      const int qq = it * THREADS + tid;
      const int r  = qq / 40;
      const int c4 = (qq - r * 40) * 4;
      float4 v;
      if (c4 < 128) v = *(const float4*)(obs + (size_t)(row0 + r) * 128 + c4);
      else          v = *(const float4*)(actions + (size_t)(row0 + r) * 32 + (c4 - 128));
      uint2 w; w.x = pack2bf(v.x, v.y); w.y = pack2bf(v.z, v.w);
      int byte = r * 320 + c4 * 2;
      byte ^= ((r & 7) << 4);
      *(uint2*)(Xb + byte) = w;
    }
  }
  __syncthreads();

  // ---- layer 1: 512 feats, K=160; direct register path ----
  f32x4 acc1[8][2];
#pragma unroll
  for (int i = 0; i < 8; ++i) { acc1[i][0] = f32x4{0,0,0,0}; acc1[i][1] = f32x4{0,0,0,0}; }
  gemm_w<160, 8, 2, 3>(W1T, smem + OFF_R, fq * 128, acc1);
  ln_silu_store<512, 8>(acc1, b1, g1, be1, smem + OFF_R, redL, fq * 128, fq);
  __syncthreads();

  // ---- layer 2: 256 feats, K=512; staged (16 chunks, 4KB slice/wave) ----
  f32x4 acc2[4][2];
#pragma unroll
  for (int i = 0; i < 4; ++i) { acc2[i][0] = f32x4{0,0,0,0}; acc2[i][1] = f32x4{0,0,0,0}; }
  gemm_staged<512, 4>(W2S, smem + OFF_R, wbuf, fq, acc2);
  ln_silu_store<256, 4>(acc2, b2, g2, be2, smem + OFF_R, redL, fq * 64, fq);
  __syncthreads();

  // ---- layer 3: 128 feats, K=256; staged (8 chunks, 2KB slice/wave) ----
  f32x4 acc3[2][2];
#pragma unroll
  for (int i = 0; i < 2; ++i) { acc3[i][0] = f32x4{0,0,0,0}; acc3[i][1] = f32x4{0,0,0,0}; }
  gemm_staged<256, 2>(W3S, smem + OFF_R, wbuf, fq, acc3);
  ln_silu_store<128, 2>(acc3, b3, g3, be3, smem + OFF_R, redL, fq * 32, fq);
  __syncthreads();

  // ---- layer 4: logits, 256pad feats, K=128; staged (4 chunks) ----
  f32x4 acc4[4][2];
#pragma unroll
  for (int i = 0; i < 4; ++i) { acc4[i][0] = f32x4{0,0,0,0}; acc4[i][1] = f32x4{0,0,0,0}; }
  gemm_staged<128, 4>(W4S, smem + OFF_R, wbuf, fq, acc4);

  float lv[4][2][4];
#pragma unroll
  for (int ft = 0; ft < 4; ++ft) {
    const int f0 = fq * 64 + ft * 16 + kg * 4;
    const f32x4 bb = *(const f32x4*)(b4L + f0);
#pragma unroll
    for (int rt = 0; rt < 2; ++rt)
#pragma unroll
      for (int rg = 0; rg < 4; ++rg) {
        const int f = f0 + rg;
        lv[ft][rt][rg] = (f < 251) ? (acc4[ft][rt][rg] + bb[rg]) : -1e30f;
      }
  }

  // ---- softmax over 251 features per row ----
#pragma unroll
  for (int rt = 0; rt < 2; ++rt) {
    float m = lv[0][rt][0];
#pragma unroll
    for (int ft = 0; ft < 4; ++ft)
#pragma unroll
      for (int rg = 0; rg < 4; ++rg) m = fmaxf(m, lv[ft][rt][rg]);
    m = fmaxf(m, __shfl_xor(m, 16));
    m = fmaxf(m, __shfl_xor(m, 32));
    if (lane < 16) redL[(rt * 16 + lm) * 5 + fq] = m;
  }
  __syncthreads();   // all waves past GEMM4's H3 reads

  float* projL = (float*)(smem + OFF_R);
  for (int i = tid; i < 32 * 251; i += THREADS) projL[i] = 0.f;

  float gm[2];
#pragma unroll
  for (int rt = 0; rt < 2; ++rt) {
    const int row = rt * 16 + lm;
    float m = redL[row * 5];
#pragma unroll
    for (int w = 1; w < 4; ++w) m = fmaxf(m, redL[row * 5 + w]);
    gm[rt] = m;
  }
  __syncthreads();
#pragma unroll
  for (int rt = 0; rt < 2; ++rt) {
    float E = 0.f;
#pragma unroll
    for (int ft = 0; ft < 4; ++ft)
#pragma unroll
      for (int rg = 0; rg < 4; ++rg) {
        float e = __expf(lv[ft][rt][rg] - gm[rt]);
        lv[ft][rt][rg] = e;
        E += e;
      }
    E += __shfl_xor(E, 16); E += __shfl_xor(E, 32);
    if (lane < 16) redL[(rt * 16 + lm) * 5 + fq] = E;
  }
  __syncthreads();
  float inv[2];
#pragma unroll
  for (int rt = 0; rt < 2; ++rt) {
    const int row = rt * 16 + lm;
    float E = 0.f;
#pragma unroll
    for (int w = 0; w < 4; ++w) E += redL[row * 5 + w];
    inv[rt] = 1.0f / E;
  }

  // ---- C51 projection scatter ----
  constexpr float DZF = 20.0f / 250.0f;
  constexpr float INVDZ = 1.0f / DZF;
#pragma unroll
  for (int ft = 0; ft < 4; ++ft) {
    const int f0 = fq * 64 + ft * 16 + kg * 4;
    const f32x4 z4 = *(const f32x4*)(zsL + f0);
#pragma unroll
    for (int rt = 0; rt < 2; ++rt) {
      const int base = (rt * 16 + lm) * 251;
      const float bd = __fmul_rn(bt[rt], dc[rt]);
#pragma unroll
      for (int rg = 0; rg < 4; ++rg) {
        const int f = f0 + rg;
        if (f < 251) {
          const float p = lv[ft][rt][rg] * inv[rt];
          float t = __fadd_rn(rw[rt], __fmul_rn(bd, z4[rg]));
          t = fminf(fmaxf(t, -10.0f), 10.0f);
          const float bfr = __fmul_rn(__fsub_rn(t, -10.0f), INVDZ);
          const float fl = floorf(bfr), fu = ceilf(bfr);
          int l = (int)fl, u = (int)fu;
          if (fl == fu) { if (l > 0) --l; else ++u; }
          atomicAdd(projL + base + l, p * ((float)u - bfr));
          atomicAdd(projL + base + u, p * (bfr - (float)l));
        }
      }
    }
  }
  __syncthreads();

  // ---- write out ----
  const float4* ps = (const float4*)projL;
  float4* po = (float4*)(out + (size_t)row0 * 251);
  for (int i = tid; i < 2008; i += THREADS) po[i] = ps[i];
}

extern "C" void kernel_launch(void* const* d_in, const int* in_sizes, int n_in,
                              void* d_out, int out_size, void* d_ws, size_t ws_size,
                              hipStream_t stream) {
  const float* obs  = (const float*)d_in[0];
  const float* act  = (const float*)d_in[1];
  const float* rew  = (const float*)d_in[2];
  const float* boot = (const float*)d_in[3];
  const float* disc = (const float*)d_in[4];
  const float* zs   = (const float*)d_in[5];
  const float* W1   = (const float*)d_in[6];
  const float* b1   = (const float*)d_in[7];
  const float* g1   = (const float*)d_in[8];
  const float* be1  = (const float*)d_in[9];
  const float* W2   = (const float*)d_in[10];
  const float* b2   = (const float*)d_in[11];
  const float* g2   = (const float*)d_in[12];
  const float* be2  = (const float*)d_in[13];
  const float* W3   = (const float*)d_in[14];
  const float* b3   = (const float*)d_in[15];
  const float* g3   = (const float*)d_in[16];
  const float* be3  = (const float*)d_in[17];
  const float* W4   = (const float*)d_in[18];
  const float* b4   = (const float*)d_in[19];
  unsigned short* wsp = (unsigned short*)d_ws;

  const int Bn = in_sizes[2];          // batch = 131072
  prep_kernel<<<(278528 + PREP_THREADS - 1) / PREP_THREADS, PREP_THREADS, 0, stream>>>(
      W1, W2, W3, W4, wsp);
  fused_kernel<<<Bn / 32, THREADS, 0, stream>>>(obs, act, rew, boot, disc, zs,
      b1, g1, be1, b2, g2, be2, b3, g3, be3, b4, wsp, (float*)d_out);
}

// Round 11
// 483.066 us; speedup vs baseline: 1.6199x; 1.0851x over previous
//
#include <hip/hip_runtime.h>

// C51 distributional Q target, R11: R5/R7 base (32 rows/block, 4 waves,
// operand-swapped MFMA, in-register LN/SiLU/softmax, 36KB time-muxed LDS,
// 4 blocks/CU) with GEMM K-loops ROLLED (#pragma unroll 1, ping-pong A0/A1
// B0/B1 static buffers, depth-2 pipeline). Tests the I-cache-bound
// hypothesis: fully-unrolled one-shot bodies (~35KB) thrash the 32KB L1I.

#define THREADS 256
#define PREP_THREADS 256

typedef __attribute__((ext_vector_type(8))) short short8v;
typedef __attribute__((ext_vector_type(4))) float f32x4;

__device__ __forceinline__ unsigned short f2bf(float f) {
  union { float f; unsigned u; } v; v.f = f;
  unsigned u = v.u;
  u += 0x7fffu + ((u >> 16) & 1u);   // RNE
  return (unsigned short)(u >> 16);
}
// HW packed fp32->bf16 (RNE), 1 VALU inst for 2 values
__device__ __forceinline__ unsigned pack2bf(float a, float b) {
  unsigned r;
  asm("v_cvt_pk_bf16_f32 %0, %1, %2" : "=v"(r) : "v"(a), "v"(b));
  return r;
}

// ---------------- prep: weights fp32 [K][N] -> bf16 [N][K] in ws -------------
// W1T @0 (512x160), W2T @81920 (256x512), W3T @212992 (128x256),
// W4T @245760 (256x128, rows n>=251 zero-padded)
__global__ void prep_kernel(const float* __restrict__ W1, const float* __restrict__ W2,
                            const float* __restrict__ W3, const float* __restrict__ W4,
                            unsigned short* __restrict__ ws) {
  int i = blockIdx.x * PREP_THREADS + threadIdx.x;
  if (i < 81920) {
    int n = i / 160, k = i - n * 160;
    ws[i] = f2bf(W1[k * 512 + n]);
  } else if (i < 212992) {
    int j = i - 81920; int n = j >> 9, k = j & 511;
    ws[i] = f2bf(W2[k * 256 + n]);
  } else if (i < 245760) {
    int j = i - 212992; int n = j >> 8, k = j & 255;
    ws[i] = f2bf(W3[k * 128 + n]);
  } else if (i < 278528) {
    int j = i - 245760; int n = j >> 7, k = j & 127;
    ws[i] = (n < 251) ? f2bf(W4[k * 251 + n]) : (unsigned short)0;
  }
}

// LDS layout (bytes). ONE time-multiplexed 32KB region R @0:
//   X bf16 [32][160] swz -> H1 [32][512] swz -> H2 [32][256] swz ->
//   H3 [32][128] swz -> proj f32 [32][251]
// Every overwrite is fenced by the LN reduction's internal __syncthreads.
#define OFF_R   0
#define OFF_ZS  32768
#define OFF_B4  33792
#define OFF_RED 34816
#define LDS_TOTAL 36096

// GEMM: acc[ft][rt] += WT[fbase+ft*16+..][k] * H[rt*16+..][k]
// MFMA 16x16x32 bf16, A = weight rows (m=feature), B = act rows (n=batch row).
// D: lane&15 = batch row in tile, (lane>>4)*4+reg = feature in tile.
// ROLLED ks-loop (#pragma unroll 1), ping-pong A0/A1,B0/B1 (static names),
// depth-2 software pipeline. acc[] indices remain compile-time (ft unrolled).
template<int KD, int NFT>
__device__ __forceinline__ void gemm_rolled(const unsigned short* __restrict__ WT,
                                            const unsigned char* __restrict__ Hb,
                                            int fbase, f32x4 (&acc)[NFT][2]) {
  constexpr int KS = KD / 32;
  const int lane = threadIdx.x & 63;
  const int lm = lane & 15, kg = lane >> 4;
  const unsigned short* wp = WT + (fbase + lm) * KD + kg * 8;
  int bbase[2], bswz[2];
#pragma unroll
  for (int rt = 0; rt < 2; ++rt) {
    const int r = rt * 16 + lm;
    bbase[rt] = r * (KD * 2) + kg * 16;
    bswz[rt] = (r & 7) << 4;
  }
  short8v A0[NFT], A1[NFT], B0[2], B1[2];

  auto loadA = [&](short8v (&A)[NFT], int k) {
#pragma unroll
    for (int ft = 0; ft < NFT; ++ft)
      A[ft] = *(const short8v*)(wp + ft * (16 * KD) + k * 32);
  };
  auto loadB = [&](short8v (&B)[2], int k) {
#pragma unroll
    for (int rt = 0; rt < 2; ++rt)
      B[rt] = *(const short8v*)(Hb + ((bbase[rt] + k * 64) ^ bswz[rt]));
  };
  auto domfma = [&](short8v (&A)[NFT], short8v (&B)[2]) {
#pragma unroll
    for (int ft = 0; ft < NFT; ++ft) {
      acc[ft][0] = __builtin_amdgcn_mfma_f32_16x16x32_bf16(A[ft], B[0], acc[ft][0], 0, 0, 0);
      acc[ft][1] = __builtin_amdgcn_mfma_f32_16x16x32_bf16(A[ft], B[1], acc[ft][1], 0, 0, 0);
    }
  };

  loadA(A0, 0); loadB(B0, 0);
  if constexpr ((KS & 1) == 0) {
#pragma unroll 1
    for (int ks = 0; ks < KS - 2; ks += 2) {
      loadA(A1, ks + 1); loadB(B1, ks + 1);
      domfma(A0, B0);
      loadA(A0, ks + 2); loadB(B0, ks + 2);
      domfma(A1, B1);
    }
    loadA(A1, KS - 1); loadB(B1, KS - 1);
    domfma(A0, B0);
    domfma(A1, B1);
  } else {
#pragma unroll 1
    for (int ks = 0; ks < KS - 1; ks += 2) {
      loadA(A1, ks + 1); loadB(B1, ks + 1);
      domfma(A0, B0);
      loadA(A0, ks + 2); loadB(B0, ks + 2);
      domfma(A1, B1);
    }
    domfma(A0, B0);   // ks = KS-1 already resident in A0/B0
  }
}

// bias + LayerNorm + SiLU entirely in registers, then one packed b64 store
// per (ft, rt) into swizzled LDS [32][ND] bf16. 4 waves reduce via redL
// (stride 9). Internal barrier doubles as the region-reuse fence.
template<int ND, int NFT>
__device__ __forceinline__ void ln_silu_store(
    f32x4 (&acc)[NFT][2],
    const float* __restrict__ bias, const float* __restrict__ g,
    const float* __restrict__ be, unsigned char* __restrict__ Hb,
    float* __restrict__ redL, int fbase, int fq)
{
  const int lane = threadIdx.x & 63;
  const int lm = lane & 15, kg = lane >> 4;
  float s[2] = {0.f, 0.f}, q[2] = {0.f, 0.f};
#pragma unroll
  for (int ft = 0; ft < NFT; ++ft) {
    const int f0 = fbase + ft * 16 + kg * 4;
    const f32x4 bb = *(const f32x4*)(bias + f0);
#pragma unroll
    for (int rt = 0; rt < 2; ++rt)
#pragma unroll
      for (int rg = 0; rg < 4; ++rg) {
        float x = acc[ft][rt][rg] + bb[rg];
        acc[ft][rt][rg] = x;
        s[rt] += x; q[rt] += x * x;
      }
  }
#pragma unroll
  for (int rt = 0; rt < 2; ++rt) {
    s[rt] += __shfl_xor(s[rt], 16); s[rt] += __shfl_xor(s[rt], 32);
    q[rt] += __shfl_xor(q[rt], 16); q[rt] += __shfl_xor(q[rt], 32);
  }
  if (lane < 16) {
#pragma unroll
    for (int rt = 0; rt < 2; ++rt) {
      redL[(rt * 16 + lm) * 9 + fq * 2    ] = s[rt];
      redL[(rt * 16 + lm) * 9 + fq * 2 + 1] = q[rt];
    }
  }
  __syncthreads();
  float mean[2], rstd[2];
#pragma unroll
  for (int rt = 0; rt < 2; ++rt) {
    const int row = rt * 16 + lm;
    float S = 0.f, Q = 0.f;
#pragma unroll
    for (int w = 0; w < 4; ++w) {
      S += redL[row * 9 + w * 2];
      Q += redL[row * 9 + w * 2 + 1];
    }
    float m = S * (1.0f / ND);
    float v = Q * (1.0f / ND) - m * m;
    mean[rt] = m; rstd[rt] = rsqrtf(v + 1e-5f);
  }
#pragma unroll
  for (int ft = 0; ft < NFT; ++ft) {
    const int f0 = fbase + ft * 16 + kg * 4;
    const f32x4 g4 = *(const f32x4*)(g + f0);
    const f32x4 e4 = *(const f32x4*)(be + f0);
#pragma unroll
    for (int rt = 0; rt < 2; ++rt) {
      const int row = rt * 16 + lm;
      float h[4];
#pragma unroll
      for (int rg = 0; rg < 4; ++rg) {
        float y = (acc[ft][rt][rg] - mean[rt]) * rstd[rt] * g4[rg] + e4[rg];
        h[rg] = y * (1.0f / (1.0f + __expf(-y)));
      }
      uint2 w; w.x = pack2bf(h[0], h[1]); w.y = pack2bf(h[2], h[3]);
      int byte = row * (ND * 2) + f0 * 2;
      byte ^= ((row & 7) << 4);
      *(uint2*)(Hb + byte) = w;
    }
  }
}

__global__ __launch_bounds__(THREADS, 4) void fused_kernel(
    const float* __restrict__ obs, const float* __restrict__ actions,
    const float* __restrict__ rewards, const float* __restrict__ bootstrap,
    const float* __restrict__ discount, const float* __restrict__ q_support,
    const float* __restrict__ b1, const float* __restrict__ g1, const float* __restrict__ be1,
    const float* __restrict__ b2, const float* __restrict__ g2, const float* __restrict__ be2,
    const float* __restrict__ b3, const float* __restrict__ g3, const float* __restrict__ be3,
    const float* __restrict__ b4,
    const unsigned short* __restrict__ ws,
    float* __restrict__ out)
{
  __shared__ __align__(16) unsigned char smem[LDS_TOTAL];
  const int tid  = threadIdx.x;
  const int fq   = tid >> 6;          // wave = feature-quarter, 0..3
  const int lane = tid & 63;
  const int lm   = lane & 15;
  const int kg   = lane >> 4;
  const int row0 = blockIdx.x * 32;

  const unsigned short* W1T = ws;
  const unsigned short* W2T = ws + 81920;
  const unsigned short* W3T = ws + 212992;
  const unsigned short* W4T = ws + 245760;

  float* zsL  = (float*)(smem + OFF_ZS);
  float* b4L  = (float*)(smem + OFF_B4);
  float* redL = (float*)(smem + OFF_RED);

  // per-row scalars straight to registers (each lane owns rows rt*16+lm)
  float rw[2], bt[2], dc[2];
#pragma unroll
  for (int rt = 0; rt < 2; ++rt) {
    const int r = row0 + rt * 16 + lm;
    rw[rt] = rewards[r]; bt[rt] = bootstrap[r]; dc[rt] = discount[r];
  }

  // stage q_support / b4 (padded to 256, avoids OOB vector loads)
  zsL[tid] = (tid < 251) ? q_support[tid] : 0.f;
  b4L[tid] = (tid < 251) ? b4[tid] : 0.f;

  // stage X = concat(obs, actions) bf16 [32][160], swizzled (1280 uint2)
  {
    unsigned char* Xb = smem + OFF_R;
#pragma unroll 1
    for (int it = 0; it < 5; ++it) {
      const int qq = it * THREADS + tid;     // 0..1279, 40 float4 per row
      const int r  = qq / 40;
      const int c4 = (qq - r * 40) * 4;
      float4 v;
      if (c4 < 128) v = *(const float4*)(obs + (size_t)(row0 + r) * 128 + c4);
      else          v = *(const float4*)(actions + (size_t)(row0 + r) * 32 + (c4 - 128));
      uint2 w; w.x = pack2bf(v.x, v.y); w.y = pack2bf(v.z, v.w);
      int byte = r * 320 + c4 * 2;
      byte ^= ((r & 7) << 4);
      *(uint2*)(Xb + byte) = w;
    }
  }
  __syncthreads();

  // ---- layer 1: 512 feats, K=160; 128 feats/wave ----
  f32x4 acc1[8][2];
#pragma unroll
  for (int i = 0; i < 8; ++i) { acc1[i][0] = f32x4{0,0,0,0}; acc1[i][1] = f32x4{0,0,0,0}; }
  gemm_rolled<160, 8>(W1T, smem + OFF_R, fq * 128, acc1);
  ln_silu_store<512, 8>(acc1, b1, g1, be1, smem + OFF_R, redL, fq * 128, fq);
  __syncthreads();

  // ---- layer 2: 256 feats, K=512; 64 feats/wave ----
  f32x4 acc2[4][2];
#pragma unroll
  for (int i = 0; i < 4; ++i) { acc2[i][0] = f32x4{0,0,0,0}; acc2[i][1] = f32x4{0,0,0,0}; }
  gemm_rolled<512, 4>(W2T, smem + OFF_R, fq * 64, acc2);
  ln_silu_store<256, 4>(acc2, b2, g2, be2, smem + OFF_R, redL, fq * 64, fq);
  __syncthreads();

  // ---- layer 3: 128 feats, K=256; 32 feats/wave ----
  f32x4 acc3[2][2];
#pragma unroll
  for (int i = 0; i < 2; ++i) { acc3[i][0] = f32x4{0,0,0,0}; acc3[i][1] = f32x4{0,0,0,0}; }
  gemm_rolled<256, 2>(W3T, smem + OFF_R, fq * 32, acc3);
  ln_silu_store<128, 2>(acc3, b3, g3, be3, smem + OFF_R, redL, fq * 32, fq);
  __syncthreads();

  // ---- layer 4: logits, 256pad feats, K=128; 64 feats/wave ----
  f32x4 acc4[4][2];
#pragma unroll
  for (int i = 0; i < 4; ++i) { acc4[i][0] = f32x4{0,0,0,0}; acc4[i][1] = f32x4{0,0,0,0}; }
  gemm_rolled<128, 4>(W4T, smem + OFF_R, fq * 64, acc4);

  float lv[4][2][4];
#pragma unroll
  for (int ft = 0; ft < 4; ++ft) {
    const int f0 = fq * 64 + ft * 16 + kg * 4;
    const f32x4 bb = *(const f32x4*)(b4L + f0);
#pragma unroll
    for (int rt = 0; rt < 2; ++rt)
#pragma unroll
      for (int rg = 0; rg < 4; ++rg) {
        const int f = f0 + rg;
        lv[ft][rt][rg] = (f < 251) ? (acc4[ft][rt][rg] + bb[rg]) : -1e30f;
      }
  }

  // ---- softmax over 251 features per row (stride-5 padded reduction) ----
#pragma unroll
  for (int rt = 0; rt < 2; ++rt) {
    float m = lv[0][rt][0];
#pragma unroll
    for (int ft = 0; ft < 4; ++ft)
#pragma unroll
      for (int rg = 0; rg < 4; ++rg) m = fmaxf(m, lv[ft][rt][rg]);
    m = fmaxf(m, __shfl_xor(m, 16));
    m = fmaxf(m, __shfl_xor(m, 32));
    if (lane < 16) redL[(rt * 16 + lm) * 5 + fq] = m;
  }
  __syncthreads();   // all waves past GEMM4's H3 reads; redL max visible

  // zero proj buffer (region R; overwrites H3 — dead now)
  float* projL = (float*)(smem + OFF_R);
  for (int i = tid; i < 32 * 251; i += THREADS) projL[i] = 0.f;

  float gm[2];
#pragma unroll
  for (int rt = 0; rt < 2; ++rt) {
    const int row = rt * 16 + lm;
    float m = redL[row * 5];
#pragma unroll
    for (int w = 1; w < 4; ++w) m = fmaxf(m, redL[row * 5 + w]);
    gm[rt] = m;
  }
  __syncthreads();   // redL reuse + proj zeros visible
#pragma unroll
  for (int rt = 0; rt < 2; ++rt) {
    float E = 0.f;
#pragma unroll
    for (int ft = 0; ft < 4; ++ft)
#pragma unroll
      for (int rg = 0; rg < 4; ++rg) {
        float e = __expf(lv[ft][rt][rg] - gm[rt]);
        lv[ft][rt][rg] = e;
        E += e;
      }
    E += __shfl_xor(E, 16); E += __shfl_xor(E, 32);
    if (lane < 16) redL[(rt * 16 + lm) * 5 + fq] = E;
  }
  __syncthreads();
  float inv[2];
#pragma unroll
  for (int rt = 0; rt < 2; ++rt) {
    const int row = rt * 16 + lm;
    float E = 0.f;
#pragma unroll
    for (int w = 0; w < 4; ++w) E += redL[row * 5 + w];
    inv[rt] = 1.0f / E;
  }

  // ---- C51 projection scatter ----
  // b = (t+10)*(1/DZ): <=1ulp off the correctly-rounded divide; the two-point
  // interpolation is continuous in b, so output error is O(1e-7).
  constexpr float DZF = 20.0f / 250.0f;
  constexpr float INVDZ = 1.0f / DZF;
#pragma unroll
  for (int ft = 0; ft < 4; ++ft) {
    const int f0 = fq * 64 + ft * 16 + kg * 4;
    const f32x4 z4 = *(const f32x4*)(zsL + f0);
#pragma unroll
    for (int rt = 0; rt < 2; ++rt) {
      const int base = (rt * 16 + lm) * 251;
      const float bd = __fmul_rn(bt[rt], dc[rt]);
#pragma unroll
      for (int rg = 0; rg < 4; ++rg) {
        const int f = f0 + rg;
        if (f < 251) {
          const float p = lv[ft][rt][rg] * inv[rt];
          float t = __fadd_rn(rw[rt], __fmul_rn(bd, z4[rg]));
          t = fminf(fmaxf(t, -10.0f), 10.0f);
          const float bfr = __fmul_rn(__fsub_rn(t, -10.0f), INVDZ);
          const float fl = floorf(bfr), fu = ceilf(bfr);
          int l = (int)fl, u = (int)fu;
          if (fl == fu) { if (l > 0) --l; else ++u; }
          atomicAdd(projL + base + l, p * ((float)u - bfr));
          atomicAdd(projL + base + u, p * (bfr - (float)l));
        }
      }
    }
  }
  __syncthreads();

  // ---- write out: block slice contiguous (32*251 floats = 2008 float4) ----
  const float4* ps = (const float4*)projL;
  float4* po = (float4*)(out + (size_t)row0 * 251);
  for (int i = tid; i < 2008; i += THREADS) po[i] = ps[i];
}

extern "C" void kernel_launch(void* const* d_in, const int* in_sizes, int n_in,
                              void* d_out, int out_size, void* d_ws, size_t ws_size,
                              hipStream_t stream) {
  const float* obs  = (const float*)d_in[0];
  const float* act  = (const float*)d_in[1];
  const float* rew  = (const float*)d_in[2];
  const float* boot = (const float*)d_in[3];
  const float* disc = (const float*)d_in[4];
  const float* zs   = (const float*)d_in[5];
  const float* W1   = (const float*)d_in[6];
  const float* b1   = (const float*)d_in[7];
  const float* g1   = (const float*)d_in[8];
  const float* be1  = (const float*)d_in[9];
  const float* W2   = (const float*)d_in[10];
  const float* b2   = (const float*)d_in[11];
  const float* g2   = (const float*)d_in[12];
  const float* be2  = (const float*)d_in[13];
  const float* W3   = (const float*)d_in[14];
  const float* b3   = (const float*)d_in[15];
  const float* g3   = (const float*)d_in[16];
  const float* be3  = (const float*)d_in[17];
  const float* W4   = (const float*)d_in[18];
  const float* b4   = (const float*)d_in[19];
  unsigned short* wsp = (unsigned short*)d_ws;

  const int Bn = in_sizes[2];          // batch = 131072
  prep_kernel<<<(278528 + PREP_THREADS - 1) / PREP_THREADS, PREP_THREADS, 0, stream>>>(
      W1, W2, W3, W4, wsp);
  fused_kernel<<<Bn / 32, THREADS, 0, stream>>>(obs, act, rew, boot, disc, zs,
      b1, g1, be1, b2, g2, be2, b3, g3, be3, b4, wsp, (float*)d_out);
}